// Round 3
// baseline (458.120 us; speedup 1.0000x reference)
//
#include <hip/hip_runtime.h>

#define ALPHA 0.9f
#define BETA  0.8f
#define K     25
#define B     128
#define T     16
#define IN_DIM 14400
#define NPB   64   // neurons per block (256 threads = 64 neurons x 4 quads)

// ---------------------------------------------------------------------------
// Transpose one 8-timestep slab of x: (B, T, IN) slab [t0,t0+8) -> xTh
// [8][IN_DIM][B]. float4 on both global sides; LDS 64x65 tile.
// ---------------------------------------------------------------------------
__global__ __launch_bounds__(256) void transpose_x4_kernel(
    const float* __restrict__ x, float* __restrict__ xTh, int t0) {
  __shared__ float tile[64][65];
  const int tl = blockIdx.z;            // local t 0..7
  const int t  = t0 + tl;
  const int i0 = blockIdx.x * 64;       // feature tile
  const int b0 = blockIdx.y * 64;       // batch tile
  const int tid = threadIdx.x;

  const int fi = (tid & 15) * 4;        // feature quad
  const int bi = tid >> 4;              // batch row 0..15
#pragma unroll
  for (int p = 0; p < 4; ++p) {
    const int b = bi + p * 16;
    const float4 v = *(const float4*)&x[(size_t)(b0 + b) * (T * IN_DIM) +
                                        (size_t)t * IN_DIM + i0 + fi];
    tile[fi + 0][b] = v.x;
    tile[fi + 1][b] = v.y;
    tile[fi + 2][b] = v.z;
    tile[fi + 3][b] = v.w;
  }
  __syncthreads();
  const int bq = (tid & 15) * 4;        // batch quad
  const int fr = tid >> 4;              // feature row 0..15
#pragma unroll
  for (int p = 0; p < 4; ++p) {
    const int f = fr + p * 16;
    float4 v;
    v.x = tile[f][bq + 0];
    v.y = tile[f][bq + 1];
    v.z = tile[f][bq + 2];
    v.w = tile[f][bq + 3];
    *(float4*)&xTh[((size_t)tl * IN_DIM + (i0 + f)) * B + b0 + bq] = v;
  }
}

// ---------------------------------------------------------------------------
// One LCN+LIF layer over nt timesteps. hsrc: [nt][dprev][B], memout:
// [nt][dim][B]. Thread = (neuron d, batch quad of 4). blockIdx%8 selects a
// 16-wide batch slice so each XCD (round-robin dispatch) only touches its
// slice's columns -> per-XCD gather working set is dprev*16*4 B (L2-fits).
// Gathers are float4 (16B/lane, 64B fully-used lines per neuron row).
// ---------------------------------------------------------------------------
__global__ __launch_bounds__(256) void lcn_layer_allt_v3(
    const float* __restrict__ hsrc, const float* __restrict__ w,
    const float* __restrict__ bias, const int* __restrict__ knn,
    float* __restrict__ memout, float* __restrict__ state,
    int dim, int dprev, int nt, int load_state, int save_state) {
  const int e  = blockIdx.x & 7;          // batch-16 slice -> XCD
  const int g  = blockIdx.x >> 3;         // neuron group
  const int nl = threadIdx.x >> 2;        // neuron within block (0..63)
  const int q  = threadIdx.x & 3;         // batch quad within slice (0..3)
  const int d  = g * NPB + nl;
  const bool act = d < dim;
  const int dc = act ? d : (dim - 1);     // clamped for loads
  const int b  = e * 16 + q * 4;

  const int dB     = dim * B;
  const int dprevB = dprev * B;

  int   idx[K];
  float wr[K];
#pragma unroll
  for (int k = 0; k < K; ++k) {
    idx[k] = knn[dc * K + k] * B + b;     // element offset incl. batch
    wr[k]  = w[dc * K + k];
  }
  const float bi = bias[dc];

  float4 s = make_float4(0.f, 0.f, 0.f, 0.f);
  float4 m = make_float4(0.f, 0.f, 0.f, 0.f);
  if (load_state) {
    s = *(const float4*)&state[(size_t)dc * B + b];
    m = *(const float4*)&state[(size_t)dB + (size_t)dc * B + b];
  }

  for (int t = 0; t < nt; ++t) {
    const float* hp = hsrc + (size_t)t * dprevB;
    float4 acc = make_float4(bi, bi, bi, bi);
#pragma unroll
    for (int k = 0; k < K; ++k) {
      const float4 h = *(const float4*)&hp[idx[k]];
      acc.x = fmaf(wr[k], h.x, acc.x);
      acc.y = fmaf(wr[k], h.y, acc.y);
      acc.z = fmaf(wr[k], h.z, acc.z);
      acc.w = fmaf(wr[k], h.w, acc.w);
    }
    s.x = ALPHA * s.x + acc.x;
    s.y = ALPHA * s.y + acc.y;
    s.z = ALPHA * s.z + acc.z;
    s.w = ALPHA * s.w + acc.w;
    float4 r;
    r.x = (m.x > 1.0f) ? 1.0f : 0.0f;   // reset from PREVIOUS membrane
    r.y = (m.y > 1.0f) ? 1.0f : 0.0f;
    r.z = (m.z > 1.0f) ? 1.0f : 0.0f;
    r.w = (m.w > 1.0f) ? 1.0f : 0.0f;
    m.x = BETA * m.x + s.x - r.x;
    m.y = BETA * m.y + s.y - r.y;
    m.z = BETA * m.z + s.z - r.z;
    m.w = BETA * m.w + s.w - r.w;
    if (act) {
      *(float4*)&memout[(size_t)t * dB + (size_t)d * B + b] = m;
    }
  }

  if (save_state && act) {
    *(float4*)&state[(size_t)d * B + b]                = s;
    *(float4*)&state[(size_t)dB + (size_t)d * B + b]   = m;
  }
}

// Final FC on the last timestep's layer-4 membrane. out[b][j], j in {0,1}.
__global__ __launch_bounds__(128) void fc_kernel(
    const float* __restrict__ mem4,  // [450][B]
    const float* __restrict__ fc_w,  // [2][450]
    const float* __restrict__ fc_b,  // [2]
    float* __restrict__ out) {       // [B][2]
  const int b = threadIdx.x;
  float a0 = fc_b[0], a1 = fc_b[1];
  for (int d = 0; d < 450; ++d) {
    const float h = mem4[d * B + b];
    a0 += fc_w[d] * h;
    a1 += fc_w[450 + d] * h;
  }
  out[b * 2 + 0] = a0;
  out[b * 2 + 1] = a1;
}

extern "C" void kernel_launch(void* const* d_in, const int* in_sizes, int n_in,
                              void* d_out, int out_size, void* d_ws,
                              size_t ws_size, hipStream_t stream) {
  (void)in_sizes; (void)n_in; (void)out_size; (void)ws_size;
  const float* x = (const float*)d_in[0];
  const float* w[5];
  const float* bias[5];
  const int* knn[5];
  for (int i = 0; i < 5; ++i) {
    w[i]    = (const float*)d_in[1 + 3 * i];
    bias[i] = (const float*)d_in[2 + 3 * i];
    knn[i]  = (const int*)d_in[3 + 3 * i];
  }
  const float* fc_w = (const float*)d_in[16];
  const float* fc_b = (const float*)d_in[17];
  float* out = (float*)d_out;

  static const int DIMS[5] = {7200, 3600, 1800, 900, 450};

  // Workspace layout (floats), 125.3 MB total (ws >= 132 MB confirmed):
  //   A  : 16*7200*128 = 14,745,600   (mem0 -> mem2 -> mem4)
  //   XB : 8*14400*128 = 14,745,600   (xT half-slab; later mem1 + mem3)
  //   S  : 2*7200*128  =  1,843,200   (layer-0 syn/mem carry between stages)
  float* A  = (float*)d_ws;
  float* XB = A + 14745600;
  float* S  = XB + 14745600;

  float* mem0 = A;                    // [16][7200][128]
  float* mem1 = XB;                   // [16][3600][128] (xT dead by then)
  float* mem2 = A;                    // [16][1800][128] (mem0 dead)
  float* mem3 = XB + 7372800;         // [16][900][128]
  float* mem4 = A;                    // [16][450][128]  (mem2 dead)

  // ---- Layer 0 in two 8-timestep stages (xT half-slab reuse) ----
  for (int stage = 0; stage < 2; ++stage) {
    const int t0 = stage * 8;
    transpose_x4_kernel<<<dim3(IN_DIM / 64, B / 64, 8), 256, 0, stream>>>(
        x, XB, t0);
    const int ng = (DIMS[0] + NPB - 1) / NPB;  // 113
    lcn_layer_allt_v3<<<ng * 8, 256, 0, stream>>>(
        XB, w[0], bias[0], knn[0], mem0 + (size_t)t0 * DIMS[0] * B, S,
        DIMS[0], IN_DIM, 8, /*load=*/stage, /*save=*/stage == 0);
  }

  // ---- Layers 1..4, all 16 timesteps each ----
  const float* src = mem0;
  float* dsts[4] = {mem1, mem2, mem3, mem4};
  for (int i = 1; i < 5; ++i) {
    const int ng = (DIMS[i] + NPB - 1) / NPB;
    lcn_layer_allt_v3<<<ng * 8, 256, 0, stream>>>(
        src, w[i], bias[i], knn[i], dsts[i - 1], nullptr, DIMS[i],
        DIMS[i - 1], 16, 0, 0);
    src = dsts[i - 1];
  }

  fc_kernel<<<1, 128, 0, stream>>>(mem4 + (size_t)15 * DIMS[4] * B, fc_w,
                                   fc_b, out);
}